// Round 13
// baseline (328.173 us; speedup 1.0000x reference)
//
#include <hip/hip_runtime.h>
#include <hip/hip_bf16.h>
#include <stdint.h>

// Problem constants
#define B_ROWS 131072
#define DD 256
#define KEXP 8
#define HH 128
#define BM 128        // rows per workgroup (4 waves x 32 rows = 2 groups of 16)
#define NW 4          // waves per workgroup

typedef float  f32x4  __attribute__((ext_vector_type(4)));
typedef short  bf16x8 __attribute__((ext_vector_type(8)));

// native bf16 cast -> v_cvt_pk_bf16_f32 (RTNE)
__device__ __forceinline__ unsigned short f2bf(float f) {
    __bf16 h = (__bf16)f;
    return __builtin_bit_cast(unsigned short, h);
}

// GELU with erf via Abramowitz-Stegun 7.1.25 (3-term, |erf err| <= 2.5e-5)
__device__ __forceinline__ float gelu_erf(float x) {
    float s = x * 0.70710678118654752f;
    float a = fabsf(s);
    float t = __builtin_amdgcn_rcpf(fmaf(0.47047f, a, 1.0f));
    float p = fmaf(t, 0.7478556f, -0.0958798f);
    p = fmaf(t, p, 0.3480242f);
    float e = __expf(-a * a);
    float Q = p * t * e;                        // = 1 - erf(a)
    float sel = (s >= 0.f) ? (2.0f - Q) : Q;    // 1 + erf(s)
    return 0.5f * x * sel;
}

__device__ __forceinline__ bf16x8 gelu_pack(f32x4 lo, f32x4 hi) {
    bf16x8 r;
    r[0] = f2bf(gelu_erf(lo[0])); r[1] = f2bf(gelu_erf(lo[1]));
    r[2] = f2bf(gelu_erf(lo[2])); r[3] = f2bf(gelu_erf(lo[3]));
    r[4] = f2bf(gelu_erf(hi[0])); r[5] = f2bf(gelu_erf(hi[1]));
    r[6] = f2bf(gelu_erf(hi[2])); r[7] = f2bf(gelu_erf(hi[3]));
    return r;
}

// Preconvert into MFMA-FRAGMENT-LINEAR order (zero-conflict LDS reads) — round-12 verified:
//   W1: [k:8][quarter q:4][frag = kk*2+hb:16][lane = g*16+c:64][j:8]
//       element = W1[(k*DD + d)*HH + h], d = kk*32 + g*8 + j, h = q*32 + hb*16 + c
//   W2: [k:8][half:2][frag = kk2*4+blk:16][lane = g*16+c:64][j:8]
//       logical k pos kl = kk2*32 + g*8 + j, source row pi(kl) (3-cycle on bits {2,3,4}:
//       h_bit4 <- k_bit2, h_bit3 <- k_bit4, h_bit2 <- k_bit3), g2 = half*64 + blk*16 + c
//       element = W2[(k*HH + pi(kl))*HH + g2]
__global__ void convert_weights(const float* __restrict__ W1, const float* __restrict__ W2,
                                uint16_t* __restrict__ w1o, uint16_t* __restrict__ w2o) {
    int idx = blockIdx.x * blockDim.x + threadIdx.x;
    const int total1 = KEXP * HH * DD;           // 262144
    if (idx < total1) {
        int k    = idx >> 15;
        int rem  = idx & 32767;
        int q    = rem >> 13;
        int r2   = rem & 8191;
        int frag = r2 >> 9;
        int r3   = r2 & 511;
        int lane = r3 >> 3;
        int j    = r3 & 7;
        int kk   = frag >> 1;
        int hb   = frag & 1;
        int g    = lane >> 4;
        int c    = lane & 15;
        int d    = kk * 32 + g * 8 + j;
        int h    = q * 32 + hb * 16 + c;
        w1o[idx] = f2bf(W1[(k * DD + d) * HH + h]);
        return;
    }
    int idx2 = idx - total1;
    const int total2 = KEXP * HH * HH;           // 131072
    if (idx2 < total2) {
        int k    = idx2 >> 14;
        int rem  = idx2 & 16383;
        int half = rem >> 13;
        int r2   = rem & 8191;
        int frag = r2 >> 9;
        int r3   = r2 & 511;
        int lane = r3 >> 3;
        int j    = r3 & 7;
        int kk2  = frag >> 2;
        int blk  = frag & 3;
        int g    = lane >> 4;
        int c    = lane & 15;
        int kl   = kk2 * 32 + g * 8 + j;         // logical k position
        int h    = (kl & ~0x1C) | ((kl & 4) << 2) | ((kl & 0x18) >> 1);  // pi (3-cycle 2->4->3->2)
        int g2   = half * 64 + blk * 16 + c;
        w2o[idx2] = f2bf(W2[(k * HH + h) * HH + g2]);
    }
}

// stage 16KB with 256 threads: 4 waves x 4 iters x (64 lanes x 16B).
__device__ __forceinline__ void stage16k(const uint16_t* __restrict__ src, uint16_t* dst,
                                         int wave, int lane) {
    const char* s = (const char*)src + wave * 1024 + lane * 16;
    char* d = (char*)dst + wave * 1024;
    #pragma unroll
    for (int i = 0; i < 4; ++i)
        __builtin_amdgcn_global_load_lds(
            (const __attribute__((address_space(1))) void*)(s + i * 4096),
            (__attribute__((address_space(3))) void*)(d + i * 4096), 16, 0, 0);
}

__global__ __launch_bounds__(256, 3)
void moe_kernel(const float* __restrict__ z, const float* __restrict__ probs,
                const float* __restrict__ b1, const float* __restrict__ b2,
                const float* __restrict__ W3, const float* __restrict__ b3,
                const uint16_t* __restrict__ w1b, const uint16_t* __restrict__ w2b,
                float* __restrict__ out) {
    __shared__ __align__(16) uint16_t wbuf[2][8192];      // 2 x 16 KB ping-pong
    __shared__ __align__(16) float preds_lds[BM * KEXP];  // 4 KB

    const int tid  = threadIdx.x;
    const int wave = tid >> 6;
    const int lane = tid & 63;
    const int c    = lane & 15;
    const int g    = lane >> 4;
    const int wg   = blockIdx.x;
    const long rowbase = (long)wg * BM;

    // two 16-row groups per wave: rows wave*32 + c (A) and wave*32 + 16 + c (B)
    bf16x8 zfA[8], zfB[8];
    {
        const float* zrA = z + (rowbase + wave * 32 + c) * DD;
        const float* zrB = zrA + 16 * DD;
        #pragma unroll
        for (int kk = 0; kk < 8; ++kk) {
            const float* pA = zrA + kk * 32 + g * 8;
            const float* pB = zrB + kk * 32 + g * 8;
            float4 x0 = *(const float4*)(pA);
            float4 x1 = *(const float4*)(pA + 4);
            bf16x8 f;
            f[0] = f2bf(x0.x); f[1] = f2bf(x0.y); f[2] = f2bf(x0.z); f[3] = f2bf(x0.w);
            f[4] = f2bf(x1.x); f[5] = f2bf(x1.y); f[6] = f2bf(x1.z); f[7] = f2bf(x1.w);
            zfA[kk] = f;
            x0 = *(const float4*)(pB);
            x1 = *(const float4*)(pB + 4);
            f[0] = f2bf(x0.x); f[1] = f2bf(x0.y); f[2] = f2bf(x0.z); f[3] = f2bf(x0.w);
            f[4] = f2bf(x1.x); f[5] = f2bf(x1.y); f[6] = f2bf(x1.z); f[7] = f2bf(x1.w);
            zfB[kk] = f;
        }
    }

    // prologue: stage expert 0, W1 quarter 0
    stage16k(w1b, wbuf[0], wave, lane);
    __syncthreads();

    int cur = 0;

    for (int ke = 0; ke < KEXP; ++ke) {
        bf16x8 paA[4], paB[4];
        const uint16_t* w1e = w1b + ke * (HH * DD);
        const uint16_t* w2e = w2b + ke * (HH * HH);
        const float* bb1 = b1 + ke * HH;

        // ---- phases A-D: layer-1 quarter q (32 h-rows, 16KB); stage next buffer ----
        #pragma unroll
        for (int q = 0; q < 4; ++q) {
            if (q < 3) stage16k(w1e + (q + 1) * 8192, wbuf[cur ^ 1], wave, lane);
            else       stage16k(w2e,                  wbuf[cur ^ 1], wave, lane);

            f32x4 b0 = *(const f32x4*)(bb1 + 32 * q +  0 + 4 * g);
            f32x4 b1v = *(const f32x4*)(bb1 + 32 * q + 16 + 4 * g);
            f32x4 a0A = b0, a1A = b1v, a0B = b0, a1B = b1v;
            const bf16x8* fb = (const bf16x8*)(wbuf[cur]) + lane;   // + frag*64 per fragment
            #pragma unroll
            for (int kk = 0; kk < 8; ++kk) {
                bf16x8 f0 = fb[kk * 128];
                bf16x8 f1 = fb[kk * 128 + 64];
                a0A = __builtin_amdgcn_mfma_f32_16x16x32_bf16(f0, zfA[kk], a0A, 0, 0, 0);
                a0B = __builtin_amdgcn_mfma_f32_16x16x32_bf16(f0, zfB[kk], a0B, 0, 0, 0);
                a1A = __builtin_amdgcn_mfma_f32_16x16x32_bf16(f1, zfA[kk], a1A, 0, 0, 0);
                a1B = __builtin_amdgcn_mfma_f32_16x16x32_bf16(f1, zfB[kk], a1B, 0, 0, 0);
            }
            paA[q] = gelu_pack(a0A, a1A);   // h rows 32q..32q+31 (pi-packed), group A
            paB[q] = gelu_pack(a0B, a1B);   // group B
            __syncthreads(); cur ^= 1;
        }

        float partA = 0.f, partB = 0.f;

        // ---- phase E: layer-2 half 0 (g2 rows 0-63) + its gelu/dot; stage W2 half 1 ----
        {
            stage16k(w2e + 8192, wbuf[cur ^ 1], wave, lane);
            const float* bb2 = b2 + ke * HH;
            f32x4 c0 = *(const f32x4*)(bb2 +  0 + 4 * g);
            f32x4 c1 = *(const f32x4*)(bb2 + 16 + 4 * g);
            f32x4 c2 = *(const f32x4*)(bb2 + 32 + 4 * g);
            f32x4 c3 = *(const f32x4*)(bb2 + 48 + 4 * g);
            f32x4 q0A = c0, q1A = c1, q2A = c2, q3A = c3;
            f32x4 q0B = c0, q1B = c1, q2B = c2, q3B = c3;
            const bf16x8* fb = (const bf16x8*)(wbuf[cur]) + lane;
            #pragma unroll
            for (int kk2 = 0; kk2 < 4; ++kk2) {
                bf16x8 f0 = fb[kk2 * 256      ];
                bf16x8 f1 = fb[kk2 * 256 +  64];
                bf16x8 f2 = fb[kk2 * 256 + 128];
                bf16x8 f3 = fb[kk2 * 256 + 192];
                q0A = __builtin_amdgcn_mfma_f32_16x16x32_bf16(f0, paA[kk2], q0A, 0, 0, 0);
                q0B = __builtin_amdgcn_mfma_f32_16x16x32_bf16(f0, paB[kk2], q0B, 0, 0, 0);
                q1A = __builtin_amdgcn_mfma_f32_16x16x32_bf16(f1, paA[kk2], q1A, 0, 0, 0);
                q1B = __builtin_amdgcn_mfma_f32_16x16x32_bf16(f1, paB[kk2], q1B, 0, 0, 0);
                q2A = __builtin_amdgcn_mfma_f32_16x16x32_bf16(f2, paA[kk2], q2A, 0, 0, 0);
                q2B = __builtin_amdgcn_mfma_f32_16x16x32_bf16(f2, paB[kk2], q2B, 0, 0, 0);
                q3A = __builtin_amdgcn_mfma_f32_16x16x32_bf16(f3, paA[kk2], q3A, 0, 0, 0);
                q3B = __builtin_amdgcn_mfma_f32_16x16x32_bf16(f3, paB[kk2], q3B, 0, 0, 0);
            }
            const float* w3p = W3 + ke * HH;
            f32x4 w3v;
            #define DOT2(qa, qb, off) \
                w3v = *(const f32x4*)(w3p + off + 4 * g); \
                partA = fmaf(gelu_erf(qa[0]), w3v[0], partA); \
                partA = fmaf(gelu_erf(qa[1]), w3v[1], partA); \
                partA = fmaf(gelu_erf(qa[2]), w3v[2], partA); \
                partA = fmaf(gelu_erf(qa[3]), w3v[3], partA); \
                partB = fmaf(gelu_erf(qb[0]), w3v[0], partB); \
                partB = fmaf(gelu_erf(qb[1]), w3v[1], partB); \
                partB = fmaf(gelu_erf(qb[2]), w3v[2], partB); \
                partB = fmaf(gelu_erf(qb[3]), w3v[3], partB);
            DOT2(q0A, q0B,  0) DOT2(q1A, q1B, 16) DOT2(q2A, q2B, 32) DOT2(q3A, q3B, 48)
            __syncthreads(); cur ^= 1;
        }

        // ---- phase F: layer-2 half 1 (g2 rows 64-127) + gelu/dot; stage next W1 q0 ----
        {
            if (ke + 1 < KEXP) stage16k(w1b + (ke + 1) * (HH * DD), wbuf[cur ^ 1], wave, lane);
            const float* bb2 = b2 + ke * HH + 64;
            f32x4 c0 = *(const f32x4*)(bb2 +  0 + 4 * g);
            f32x4 c1 = *(const f32x4*)(bb2 + 16 + 4 * g);
            f32x4 c2 = *(const f32x4*)(bb2 + 32 + 4 * g);
            f32x4 c3 = *(const f32x4*)(bb2 + 48 + 4 * g);
            f32x4 q4A = c0, q5A = c1, q6A = c2, q7A = c3;
            f32x4 q4B = c0, q5B = c1, q6B = c2, q7B = c3;
            const bf16x8* fb = (const bf16x8*)(wbuf[cur]) + lane;
            #pragma unroll
            for (int kk2 = 0; kk2 < 4; ++kk2) {
                bf16x8 f0 = fb[kk2 * 256      ];
                bf16x8 f1 = fb[kk2 * 256 +  64];
                bf16x8 f2 = fb[kk2 * 256 + 128];
                bf16x8 f3 = fb[kk2 * 256 + 192];
                q4A = __builtin_amdgcn_mfma_f32_16x16x32_bf16(f0, paA[kk2], q4A, 0, 0, 0);
                q4B = __builtin_amdgcn_mfma_f32_16x16x32_bf16(f0, paB[kk2], q4B, 0, 0, 0);
                q5A = __builtin_amdgcn_mfma_f32_16x16x32_bf16(f1, paA[kk2], q5A, 0, 0, 0);
                q5B = __builtin_amdgcn_mfma_f32_16x16x32_bf16(f1, paB[kk2], q5B, 0, 0, 0);
                q6A = __builtin_amdgcn_mfma_f32_16x16x32_bf16(f2, paA[kk2], q6A, 0, 0, 0);
                q6B = __builtin_amdgcn_mfma_f32_16x16x32_bf16(f2, paB[kk2], q6B, 0, 0, 0);
                q7A = __builtin_amdgcn_mfma_f32_16x16x32_bf16(f3, paA[kk2], q7A, 0, 0, 0);
                q7B = __builtin_amdgcn_mfma_f32_16x16x32_bf16(f3, paB[kk2], q7B, 0, 0, 0);
            }
            const float* w3p = W3 + ke * HH + 64;
            f32x4 w3v;
            DOT2(q4A, q4B,  0) DOT2(q5A, q5B, 16) DOT2(q6A, q6B, 32) DOT2(q7A, q7B, 48)
            #undef DOT2
            partA += __shfl_xor(partA, 16);
            partA += __shfl_xor(partA, 32);
            partB += __shfl_xor(partB, 16);
            partB += __shfl_xor(partB, 32);
            if (g == 0) {
                float b3v = b3[ke];
                preds_lds[(wave * 32 + c) * KEXP + ke]      = partA + b3v;
                preds_lds[(wave * 32 + 16 + c) * KEXP + ke] = partB + b3v;
            }
            __syncthreads(); cur ^= 1;
        }
    }

    // expert_preds: coalesced 1024 f32 per WG
    {
        float4 v = *(const float4*)(preds_lds + tid * 4);
        *(float4*)(out + B_ROWS + rowbase * KEXP + tid * 4) = v;
    }
    // blended: 128 f32 per WG (probs straight from global, coalesced)
    if (tid < BM) {
        const float* pr = probs + (rowbase + tid) * KEXP;
        float4 p0 = *(const float4*)(pr);
        float4 p1 = *(const float4*)(pr + 4);
        const float* pd = preds_lds + tid * KEXP;
        float s = 0.f;
        s = fmaf(p0.x, pd[0], s); s = fmaf(p0.y, pd[1], s);
        s = fmaf(p0.z, pd[2], s); s = fmaf(p0.w, pd[3], s);
        s = fmaf(p1.x, pd[4], s); s = fmaf(p1.y, pd[5], s);
        s = fmaf(p1.z, pd[6], s); s = fmaf(p1.w, pd[7], s);
        out[rowbase + tid] = s;
    }
}

extern "C" void kernel_launch(void* const* d_in, const int* in_sizes, int n_in,
                              void* d_out, int out_size, void* d_ws, size_t ws_size,
                              hipStream_t stream) {
    const float* z     = (const float*)d_in[0];
    const float* probs = (const float*)d_in[1];
    const float* W1    = (const float*)d_in[2];
    const float* b1    = (const float*)d_in[3];
    const float* W2    = (const float*)d_in[4];
    const float* b2    = (const float*)d_in[5];
    const float* W3    = (const float*)d_in[6];
    const float* b3    = (const float*)d_in[7];
    float* out = (float*)d_out;

    uint16_t* w1b = (uint16_t*)d_ws;                       // 8*128*256 bf16 = 512 KB
    uint16_t* w2b = w1b + (size_t)KEXP * HH * DD;          // 8*128*128 bf16 = 256 KB

    const int totalw = KEXP * HH * DD + KEXP * HH * HH;    // 393216
    convert_weights<<<(totalw + 255) / 256, 256, 0, stream>>>(W1, W2, w1b, w2b);
    moe_kernel<<<B_ROWS / BM, 256, 0, stream>>>(z, probs, b1, b2, W3, b3, w1b, w2b, out);
}

// Round 14
// 181.775 us; speedup vs baseline: 1.8054x; 1.8054x over previous
//
#include <hip/hip_runtime.h>
#include <hip/hip_bf16.h>
#include <stdint.h>

// Problem constants
#define B_ROWS 131072
#define DD 256
#define KEXP 8
#define HH 128
#define BM 64         // rows per workgroup (4 waves x 16 rows)
#define NW 4          // waves per workgroup

typedef float  f32x4  __attribute__((ext_vector_type(4)));
typedef short  bf16x8 __attribute__((ext_vector_type(8)));

// native bf16 cast -> v_cvt_pk_bf16_f32 (RTNE)
__device__ __forceinline__ unsigned short f2bf(float f) {
    __bf16 h = (__bf16)f;
    return __builtin_bit_cast(unsigned short, h);
}

// Branch-free tanh-form GELU: gelu(x) = x - x / (e^{x(k1 + k2 x^2)} + 1),
// k1 = 2*sqrt(2/pi), k2 = k1*0.044715. Max |delta| vs exact-erf gelu ~5e-4,
// well under the bf16 chain noise. Tails saturate correctly (E->inf => x, E->0 => 0).
__device__ __forceinline__ float gelu_fast(float x) {
    float x2 = x * x;
    float w  = fmaf(x2, 0.07135481627f, 1.59576912161f);
    float E  = __expf(x * w);
    float t  = __builtin_amdgcn_rcpf(E + 1.0f);
    return fmaf(-x, t, x);
}

__device__ __forceinline__ bf16x8 gelu_pack(f32x4 lo, f32x4 hi) {
    bf16x8 r;
    r[0] = f2bf(gelu_fast(lo[0])); r[1] = f2bf(gelu_fast(lo[1]));
    r[2] = f2bf(gelu_fast(lo[2])); r[3] = f2bf(gelu_fast(lo[3]));
    r[4] = f2bf(gelu_fast(hi[0])); r[5] = f2bf(gelu_fast(hi[1]));
    r[6] = f2bf(gelu_fast(hi[2])); r[7] = f2bf(gelu_fast(hi[3]));
    return r;
}

// Preconvert into MFMA-FRAGMENT-LINEAR order (zero-conflict LDS reads) — round-12 verified:
//   W1: [k:8][quarter q:4][frag = kk*2+hb:16][lane = g*16+c:64][j:8]
//       element = W1[(k*DD + d)*HH + h], d = kk*32 + g*8 + j, h = q*32 + hb*16 + c
//   W2: [k:8][half:2][frag = kk2*4+blk:16][lane = g*16+c:64][j:8]
//       logical k pos kl = kk2*32 + g*8 + j, source row pi(kl) (3-cycle on bits {2,3,4}:
//       h_bit4 <- k_bit2, h_bit3 <- k_bit4, h_bit2 <- k_bit3), g2 = half*64 + blk*16 + c
//       element = W2[(k*HH + pi(kl))*HH + g2]
__global__ void convert_weights(const float* __restrict__ W1, const float* __restrict__ W2,
                                uint16_t* __restrict__ w1o, uint16_t* __restrict__ w2o) {
    int idx = blockIdx.x * blockDim.x + threadIdx.x;
    const int total1 = KEXP * HH * DD;           // 262144
    if (idx < total1) {
        int k    = idx >> 15;
        int rem  = idx & 32767;
        int q    = rem >> 13;
        int r2   = rem & 8191;
        int frag = r2 >> 9;
        int r3   = r2 & 511;
        int lane = r3 >> 3;
        int j    = r3 & 7;
        int kk   = frag >> 1;
        int hb   = frag & 1;
        int g    = lane >> 4;
        int c    = lane & 15;
        int d    = kk * 32 + g * 8 + j;
        int h    = q * 32 + hb * 16 + c;
        w1o[idx] = f2bf(W1[(k * DD + d) * HH + h]);
        return;
    }
    int idx2 = idx - total1;
    const int total2 = KEXP * HH * HH;           // 131072
    if (idx2 < total2) {
        int k    = idx2 >> 14;
        int rem  = idx2 & 16383;
        int half = rem >> 13;
        int r2   = rem & 8191;
        int frag = r2 >> 9;
        int r3   = r2 & 511;
        int lane = r3 >> 3;
        int j    = r3 & 7;
        int kk2  = frag >> 2;
        int blk  = frag & 3;
        int g    = lane >> 4;
        int c    = lane & 15;
        int kl   = kk2 * 32 + g * 8 + j;         // logical k position
        int h    = (kl & ~0x1C) | ((kl & 4) << 2) | ((kl & 0x18) >> 1);  // pi (3-cycle 2->4->3->2)
        int g2   = half * 64 + blk * 16 + c;
        w2o[idx2] = f2bf(W2[(k * HH + h) * HH + g2]);
    }
}

// stage 16KB with 256 threads: 4 waves x 4 iters x (64 lanes x 16B).
// LDS dest is wave-uniform base + lane*16 (HW rule); source is the linear image above.
__device__ __forceinline__ void stage16k(const uint16_t* __restrict__ src, uint16_t* dst,
                                         int wave, int lane) {
    const char* s = (const char*)src + wave * 1024 + lane * 16;
    char* d = (char*)dst + wave * 1024;
    #pragma unroll
    for (int i = 0; i < 4; ++i)
        __builtin_amdgcn_global_load_lds(
            (const __attribute__((address_space(1))) void*)(s + i * 4096),
            (__attribute__((address_space(3))) void*)(d + i * 4096), 16, 0, 0);
}

__global__ __launch_bounds__(256, 4)
void moe_kernel(const float* __restrict__ z, const float* __restrict__ probs,
                const float* __restrict__ b1, const float* __restrict__ b2,
                const float* __restrict__ W3, const float* __restrict__ b3,
                const uint16_t* __restrict__ w1b, const uint16_t* __restrict__ w2b,
                float* __restrict__ out) {
    __shared__ __align__(16) uint16_t wbuf[2][8192];      // 2 x 16 KB ping-pong
    __shared__ __align__(16) float preds_lds[BM * KEXP];  // 2 KB

    const int tid  = threadIdx.x;
    const int wave = tid >> 6;
    const int lane = tid & 63;
    const int c    = lane & 15;
    const int g    = lane >> 4;
    const int wg   = blockIdx.x;
    const long rowbase = (long)wg * BM;

    // z fragments in registers: lane holds z[row = wave*16 + c][d = kk*32 + 8g + j]
    bf16x8 zf[8];
    {
        const float* zr = z + (rowbase + wave * 16 + c) * DD;
        #pragma unroll
        for (int kk = 0; kk < 8; ++kk) {
            const float* p = zr + kk * 32 + g * 8;
            float4 x0 = *(const float4*)(p);
            float4 x1 = *(const float4*)(p + 4);
            bf16x8 f;
            f[0] = f2bf(x0.x); f[1] = f2bf(x0.y); f[2] = f2bf(x0.z); f[3] = f2bf(x0.w);
            f[4] = f2bf(x1.x); f[5] = f2bf(x1.y); f[6] = f2bf(x1.z); f[7] = f2bf(x1.w);
            zf[kk] = f;
        }
    }

    // prologue: stage expert 0, W1 quarter 0
    stage16k(w1b, wbuf[0], wave, lane);
    __syncthreads();

    int cur = 0;

    for (int ke = 0; ke < KEXP; ++ke) {
        bf16x8 pa[4];
        const uint16_t* w1e = w1b + ke * (HH * DD);
        const uint16_t* w2e = w2b + ke * (HH * HH);
        const float* bb1 = b1 + ke * HH;

        // ---- phases A-D: layer-1 quarter q (32 h-rows, 16KB); stage next buffer ----
        #pragma unroll
        for (int q = 0; q < 4; ++q) {
            // stage: q<3 -> W1 quarter q+1 ; q==3 -> W2 half 0
            if (q < 3) stage16k(w1e + (q + 1) * 8192, wbuf[cur ^ 1], wave, lane);
            else       stage16k(w2e,                  wbuf[cur ^ 1], wave, lane);

            f32x4 a0 = *(const f32x4*)(bb1 + 32 * q +  0 + 4 * g);
            f32x4 a1 = *(const f32x4*)(bb1 + 32 * q + 16 + 4 * g);
            const bf16x8* fb = (const bf16x8*)(wbuf[cur]) + lane;   // + frag*64 per fragment
            #pragma unroll
            for (int kk = 0; kk < 8; ++kk) {
                a0 = __builtin_amdgcn_mfma_f32_16x16x32_bf16(fb[kk * 128     ], zf[kk], a0, 0, 0, 0);
                a1 = __builtin_amdgcn_mfma_f32_16x16x32_bf16(fb[kk * 128 + 64], zf[kk], a1, 0, 0, 0);
            }
            pa[q] = gelu_pack(a0, a1);   // h rows 32q..32q+31 (pi-packed)
            __syncthreads(); cur ^= 1;
        }

        // ---- phase E: layer-2 half 0 (g2 rows 0-63); stage W2 half 1 ----
        f32x4 q0, q1, q2, q3;
        {
            stage16k(w2e + 8192, wbuf[cur ^ 1], wave, lane);
            const float* bb2 = b2 + ke * HH;
            q0 = *(const f32x4*)(bb2 +  0 + 4 * g);
            q1 = *(const f32x4*)(bb2 + 16 + 4 * g);
            q2 = *(const f32x4*)(bb2 + 32 + 4 * g);
            q3 = *(const f32x4*)(bb2 + 48 + 4 * g);
            const bf16x8* fb = (const bf16x8*)(wbuf[cur]) + lane;
            #pragma unroll
            for (int kk2 = 0; kk2 < 4; ++kk2) {
                q0 = __builtin_amdgcn_mfma_f32_16x16x32_bf16(fb[kk2 * 256      ], pa[kk2], q0, 0, 0, 0);
                q1 = __builtin_amdgcn_mfma_f32_16x16x32_bf16(fb[kk2 * 256 +  64], pa[kk2], q1, 0, 0, 0);
                q2 = __builtin_amdgcn_mfma_f32_16x16x32_bf16(fb[kk2 * 256 + 128], pa[kk2], q2, 0, 0, 0);
                q3 = __builtin_amdgcn_mfma_f32_16x16x32_bf16(fb[kk2 * 256 + 192], pa[kk2], q3, 0, 0, 0);
            }
            __syncthreads(); cur ^= 1;
        }

        // ---- phase F: layer-2 half 1 (g2 rows 64-127); stage next expert's Q0; dot ----
        {
            if (ke + 1 < KEXP) stage16k(w1b + (ke + 1) * (HH * DD), wbuf[cur ^ 1], wave, lane);
            const float* bb2 = b2 + ke * HH + 64;
            f32x4 q4 = *(const f32x4*)(bb2 +  0 + 4 * g);
            f32x4 q5 = *(const f32x4*)(bb2 + 16 + 4 * g);
            f32x4 q6 = *(const f32x4*)(bb2 + 32 + 4 * g);
            f32x4 q7 = *(const f32x4*)(bb2 + 48 + 4 * g);
            const bf16x8* fb = (const bf16x8*)(wbuf[cur]) + lane;
            #pragma unroll
            for (int kk2 = 0; kk2 < 4; ++kk2) {
                q4 = __builtin_amdgcn_mfma_f32_16x16x32_bf16(fb[kk2 * 256      ], pa[kk2], q4, 0, 0, 0);
                q5 = __builtin_amdgcn_mfma_f32_16x16x32_bf16(fb[kk2 * 256 +  64], pa[kk2], q5, 0, 0, 0);
                q6 = __builtin_amdgcn_mfma_f32_16x16x32_bf16(fb[kk2 * 256 + 128], pa[kk2], q6, 0, 0, 0);
                q7 = __builtin_amdgcn_mfma_f32_16x16x32_bf16(fb[kk2 * 256 + 192], pa[kk2], q7, 0, 0, 0);
            }

            // GELU + layer-3 dot: lane holds g2 = 16*hb2 + 4g + r, m = c
            const float* w3p = W3 + ke * HH;
            float part = 0.f;
            f32x4 w3v;
            #define DOT(qq, off) \
                w3v = *(const f32x4*)(w3p + off + 4 * g); \
                part = fmaf(gelu_fast(qq[0]), w3v[0], part); \
                part = fmaf(gelu_fast(qq[1]), w3v[1], part); \
                part = fmaf(gelu_fast(qq[2]), w3v[2], part); \
                part = fmaf(gelu_fast(qq[3]), w3v[3], part);
            DOT(q0,   0) DOT(q1,  16) DOT(q2,  32) DOT(q3,  48)
            DOT(q4,  64) DOT(q5,  80) DOT(q6,  96) DOT(q7, 112)
            #undef DOT
            part += __shfl_xor(part, 16);
            part += __shfl_xor(part, 32);
            if (g == 0)
                preds_lds[(wave * 16 + c) * KEXP + ke] = part + b3[ke];
            __syncthreads(); cur ^= 1;
        }
    }

    // expert_preds: coalesced 512 f32 per WG
    {
        float2 v = *(const float2*)(preds_lds + tid * 2);
        *(float2*)(out + B_ROWS + rowbase * KEXP + tid * 2) = v;
    }
    // blended: 64 f32 per WG (probs straight from global, coalesced)
    if (tid < BM) {
        const float* pr = probs + (rowbase + tid) * KEXP;
        float4 p0 = *(const float4*)(pr);
        float4 p1 = *(const float4*)(pr + 4);
        const float* pd = preds_lds + tid * KEXP;
        float s = 0.f;
        s = fmaf(p0.x, pd[0], s); s = fmaf(p0.y, pd[1], s);
        s = fmaf(p0.z, pd[2], s); s = fmaf(p0.w, pd[3], s);
        s = fmaf(p1.x, pd[4], s); s = fmaf(p1.y, pd[5], s);
        s = fmaf(p1.z, pd[6], s); s = fmaf(p1.w, pd[7], s);
        out[rowbase + tid] = s;
    }
}

extern "C" void kernel_launch(void* const* d_in, const int* in_sizes, int n_in,
                              void* d_out, int out_size, void* d_ws, size_t ws_size,
                              hipStream_t stream) {
    const float* z     = (const float*)d_in[0];
    const float* probs = (const float*)d_in[1];
    const float* W1    = (const float*)d_in[2];
    const float* b1    = (const float*)d_in[3];
    const float* W2    = (const float*)d_in[4];
    const float* b2    = (const float*)d_in[5];
    const float* W3    = (const float*)d_in[6];
    const float* b3    = (const float*)d_in[7];
    float* out = (float*)d_out;

    uint16_t* w1b = (uint16_t*)d_ws;                       // 8*128*256 bf16 = 512 KB
    uint16_t* w2b = w1b + (size_t)KEXP * HH * DD;          // 8*128*128 bf16 = 256 KB

    const int totalw = KEXP * HH * DD + KEXP * HH * HH;    // 393216
    convert_weights<<<(totalw + 255) / 256, 256, 0, stream>>>(W1, W2, w1b, w2b);
    moe_kernel<<<B_ROWS / BM, 256, 0, stream>>>(z, probs, b1, b2, W3, b3, w1b, w2b, out);
}